// Round 1
// baseline (374.096 us; speedup 1.0000x reference)
//
#include <hip/hip_runtime.h>

#define B_ 32
#define T_ 2048
#define H_ 1024
#define S_ 8
#define V_ 32768
#define ROWS 256    // B_*S_
#define OUTO 8192   // S_*H_
#define NCHUNK 16
#define TCHUNK 128

// ---------------- kernel 1: masked pooling partials ----------------
__global__ void pool_kernel(const float* __restrict__ hidden,
                            const int* __restrict__ mask,
                            float* __restrict__ part_pool,   // [NCHUNK][H_*B_] as [h][b]
                            int* __restrict__ cntpart) {     // [NCHUNK][B_]
  int b = blockIdx.x;
  int chunk = blockIdx.y;
  int t0 = chunk * TCHUNK;
  int h4 = threadIdx.x * 4;
  const float* base = hidden + ((size_t)b * T_ + t0) * H_ + h4;
  const int* mrow = mask + (size_t)b * T_ + t0;
  float a0 = 0.f, a1 = 0.f, a2 = 0.f, a3 = 0.f;
  int mcount = 0;
#pragma unroll 4
  for (int i = 0; i < TCHUNK; ++i) {
    int mi = mrow[i];
    float m = (float)mi;
    mcount += mi;
    float4 v = *reinterpret_cast<const float4*>(base + (size_t)i * H_);
    a0 += m * v.x; a1 += m * v.y; a2 += m * v.z; a3 += m * v.w;
  }
  float* pp = part_pool + (size_t)chunk * (H_ * B_);
  pp[(h4 + 0) * B_ + b] = a0;
  pp[(h4 + 1) * B_ + b] = a1;
  pp[(h4 + 2) * B_ + b] = a2;
  pp[(h4 + 3) * B_ + b] = a3;
  if (threadIdx.x == 0) cntpart[chunk * B_ + b] = mcount;
}

// ---------------- kernel 1b: reduce partials -> pooledT [h][b] ----------------
__global__ void pool_reduce_kernel(const float* __restrict__ part_pool,
                                   const int* __restrict__ cntpart,
                                   float* __restrict__ pooledT,
                                   int* __restrict__ cnt) {
  int g = blockIdx.x * 256 + threadIdx.x;  // 0..32767 over (h,b)
  float s = 0.f;
  for (int c = 0; c < NCHUNK; ++c) s += part_pool[(size_t)c * (H_ * B_) + g];
  pooledT[g] = s;
  if (g < B_) {
    int cs = 0;
    for (int c = 0; c < NCHUNK; ++c) cs += cntpart[c * B_ + g];
    cnt[g] = cs;
  }
}

// ---------------- kernel 2: pre_q = pooled @ W^T (per-element) ----------------
__global__ void proj_kernel(const float* __restrict__ Wp,
                            const float* __restrict__ pooledT,
                            const int* __restrict__ cnt,
                            float* __restrict__ preq) {
  int t = threadIdx.x;
  int olocal = t >> 5;                 // 0..7, lanes 0-31 share o (broadcast W reads)
  int o = blockIdx.x * 8 + olocal;
  int b = t & 31;
  const float* wrow = Wp + (size_t)o * H_;
  float acc = 0.f;
#pragma unroll 4
  for (int k = 0; k < H_; k += 4) {
    float4 w4 = *reinterpret_cast<const float4*>(wrow + k);
    float p0 = pooledT[(k + 0) * B_ + b];
    float p1 = pooledT[(k + 1) * B_ + b];
    float p2 = pooledT[(k + 2) * B_ + b];
    float p3 = pooledT[(k + 3) * B_ + b];
    acc += w4.x * p0 + w4.y * p1 + w4.z * p2 + w4.w * p3;
  }
  float denom = fmaxf((float)cnt[b], 1.0f);
  float val = acc / denom;
  __shared__ float xch[8][32];
  xch[olocal][b] = val;
  __syncthreads();
  int b2 = t >> 3, j = t & 7;          // coalesced-ish transpose store
  preq[(size_t)b2 * OUTO + blockIdx.x * 8 + j] = xch[j][b2];
}

// ---------------- kernel 2b: xnorm[row] = sum(pre_q^2) ----------------
__global__ void xnorm_kernel(const float* __restrict__ preq, float* __restrict__ xnorm) {
  int row = blockIdx.x;
  int t = threadIdx.x;
  float4 v = reinterpret_cast<const float4*>(preq + (size_t)row * H_)[t];
  float s = v.x * v.x + v.y * v.y + v.z * v.z + v.w * v.w;
#pragma unroll
  for (int off = 1; off < 64; off <<= 1) s += __shfl_xor(s, off, 64);
  __shared__ float ps[4];
  if ((t & 63) == 0) ps[t >> 6] = s;
  __syncthreads();
  if (t == 0) xnorm[row] = ps[0] + ps[1] + ps[2] + ps[3];
}

// ---------------- kernel 3: fused distance GEMM + logits + block argmax ----------------
#define KT 32
#define NT 64
#define APAD 260
#define BPAD 68

__global__ __launch_bounds__(256) void dist_kernel(
    const float* __restrict__ preq, const float* __restrict__ codebook,
    const float* __restrict__ xnorm, float* __restrict__ logits,
    float* __restrict__ pscore, int* __restrict__ pidx) {
  __shared__ float As[KT][APAD];   // k-major, padded (stride 1040B, 16B-aligned)
  __shared__ float Bs[KT][BPAD];
  __shared__ float cn[NT];
  int t = threadIdx.x;
  int blk = blockIdx.x;
  int v0 = blk * NT;
  int tr = t >> 3, tc = t & 7;     // tr: 0..31, tc: 0..7
  float acc[8][8] = {};
  float csq0 = 0.f, csq1 = 0.f;

  for (int kt = 0; kt < H_ / KT; ++kt) {
    int k0 = kt * KT;
    __syncthreads();
    // stage A tile [256 rows][32 k] -> As[k][row]
#pragma unroll
    for (int i = 0; i < 8; ++i) {
      int r = i * 32 + tr;
      float4 av = *reinterpret_cast<const float4*>(&preq[(size_t)r * H_ + k0 + 4 * tc]);
      As[4 * tc + 0][r] = av.x; As[4 * tc + 1][r] = av.y;
      As[4 * tc + 2][r] = av.z; As[4 * tc + 3][r] = av.w;
    }
    // stage B tile [64 cols][32 k] -> Bs[k][v], accumulate cnorm partials
    {
      float4 bv = *reinterpret_cast<const float4*>(&codebook[(size_t)(v0 + tr) * H_ + k0 + 4 * tc]);
      Bs[4 * tc + 0][tr] = bv.x; Bs[4 * tc + 1][tr] = bv.y;
      Bs[4 * tc + 2][tr] = bv.z; Bs[4 * tc + 3][tr] = bv.w;
      csq0 += bv.x * bv.x + bv.y * bv.y + bv.z * bv.z + bv.w * bv.w;
      float4 bw = *reinterpret_cast<const float4*>(&codebook[(size_t)(v0 + 32 + tr) * H_ + k0 + 4 * tc]);
      Bs[4 * tc + 0][32 + tr] = bw.x; Bs[4 * tc + 1][32 + tr] = bw.y;
      Bs[4 * tc + 2][32 + tr] = bw.z; Bs[4 * tc + 3][32 + tr] = bw.w;
      csq1 += bw.x * bw.x + bw.y * bw.y + bw.z * bw.z + bw.w * bw.w;
    }
    __syncthreads();
#pragma unroll 4
    for (int k = 0; k < KT; ++k) {
      float4 a0 = *reinterpret_cast<const float4*>(&As[k][tr * 8]);
      float4 a1 = *reinterpret_cast<const float4*>(&As[k][tr * 8 + 4]);
      float4 b0 = *reinterpret_cast<const float4*>(&Bs[k][tc * 8]);
      float4 b1 = *reinterpret_cast<const float4*>(&Bs[k][tc * 8 + 4]);
      float a[8]  = {a0.x, a0.y, a0.z, a0.w, a1.x, a1.y, a1.z, a1.w};
      float bb[8] = {b0.x, b0.y, b0.z, b0.w, b1.x, b1.y, b1.z, b1.w};
#pragma unroll
      for (int i = 0; i < 8; ++i)
#pragma unroll
        for (int j = 0; j < 8; ++j)
          acc[i][j] += a[i] * bb[j];
    }
  }

  // finish cnorm: reduce csq over the 8 tc lanes (consecutive lanes, same tr)
#pragma unroll
  for (int off = 1; off < 8; off <<= 1) {
    csq0 += __shfl_xor(csq0, off, 64);
    csq1 += __shfl_xor(csq1, off, 64);
  }
  if (tc == 0) { cn[tr] = csq0; cn[32 + tr] = csq1; }
  __syncthreads();

  float xn[8], cnr[8];
#pragma unroll
  for (int i = 0; i < 8; ++i) xn[i] = xnorm[tr * 8 + i];
#pragma unroll
  for (int j = 0; j < 8; ++j) cnr[j] = cn[tc * 8 + j];

  float best[8]; int bix[8];
#pragma unroll
  for (int i = 0; i < 8; ++i) {
    float lg[8];
    float bs = -3.402823466e38f; int bi = 0;
#pragma unroll
    for (int j = 0; j < 8; ++j) {
      float sc = 2.f * acc[i][j] - cnr[j];   // score: argmax(sc) == argmax(logit) per row
      lg[j] = sc - xn[i];                    // logit = 2*dot - ||x||^2 - ||c||^2
      if (sc > bs) { bs = sc; bi = v0 + tc * 8 + j; }  // ascending j => first-max tie-break
    }
    best[i] = bs; bix[i] = bi;
    float* lp = &logits[(size_t)(tr * 8 + i) * V_ + v0 + tc * 8];
    reinterpret_cast<float4*>(lp)[0] = make_float4(lg[0], lg[1], lg[2], lg[3]);
    reinterpret_cast<float4*>(lp)[1] = make_float4(lg[4], lg[5], lg[6], lg[7]);
  }

  // reduce (best,idx) across the 8 tc lanes; prefer higher score, then lower index
#pragma unroll
  for (int off = 1; off < 8; off <<= 1) {
#pragma unroll
    for (int i = 0; i < 8; ++i) {
      float os = __shfl_xor(best[i], off, 64);
      int oi = __shfl_xor(bix[i], off, 64);
      if (os > best[i] || (os == best[i] && oi < bix[i])) { best[i] = os; bix[i] = oi; }
    }
  }
  if (tc == 0) {
#pragma unroll
    for (int i = 0; i < 8; ++i) {
      pscore[(size_t)(tr * 8 + i) * 512 + blk] = best[i];
      pidx[(size_t)(tr * 8 + i) * 512 + blk] = bix[i];
    }
  }
}

// ---------------- kernel 4: per-row argmax over blocks, gather, quantized, loss partial ----------------
__global__ void finalize_kernel(const float* __restrict__ preq,
                                const float* __restrict__ codebook,
                                const float* __restrict__ pscore,
                                const int* __restrict__ pidx,
                                float* __restrict__ out_idx,
                                float* __restrict__ out_quant,
                                float* __restrict__ lsum) {
  int row = blockIdx.x;
  int t = threadIdx.x;
  float bs = -3.402823466e38f; int bi = 0x7fffffff;
  for (int p = t; p < 512; p += 256) {
    float s = pscore[(size_t)row * 512 + p];
    int ix = pidx[(size_t)row * 512 + p];
    if (s > bs || (s == bs && ix < bi)) { bs = s; bi = ix; }
  }
#pragma unroll
  for (int off = 1; off < 64; off <<= 1) {
    float os = __shfl_xor(bs, off, 64);
    int oi = __shfl_xor(bi, off, 64);
    if (os > bs || (os == bs && oi < bi)) { bs = os; bi = oi; }
  }
  __shared__ float ss[4]; __shared__ int si[4]; __shared__ int fidx;
  if ((t & 63) == 0) { ss[t >> 6] = bs; si[t >> 6] = bi; }
  __syncthreads();
  if (t == 0) {
    float b0 = ss[0]; int i0 = si[0];
    for (int w = 1; w < 4; ++w)
      if (ss[w] > b0 || (ss[w] == b0 && si[w] < i0)) { b0 = ss[w]; i0 = si[w]; }
    fidx = i0;
    out_idx[row] = (float)i0;
  }
  __syncthreads();
  int idx = fidx;
  float4 e = reinterpret_cast<const float4*>(codebook + (size_t)idx * H_)[t];
  float4 p = reinterpret_cast<const float4*>(preq + (size_t)row * H_)[t];
  float4 q;
  q.x = p.x + (e.x - p.x); q.y = p.y + (e.y - p.y);
  q.z = p.z + (e.z - p.z); q.w = p.w + (e.w - p.w);
  reinterpret_cast<float4*>(out_quant)[row * 256 + t] = q;
  float dx = p.x - e.x, dy = p.y - e.y, dz = p.z - e.z, dw = p.w - e.w;
  float ls = dx * dx + dy * dy + dz * dz + dw * dw;
#pragma unroll
  for (int off = 1; off < 64; off <<= 1) ls += __shfl_xor(ls, off, 64);
  __shared__ float lss[4];
  if ((t & 63) == 0) lss[t >> 6] = ls;
  __syncthreads();
  if (t == 0) lsum[row] = lss[0] + lss[1] + lss[2] + lss[3];
}

// ---------------- kernel 5: final losses ----------------
__global__ void loss_kernel(const float* __restrict__ lsum, float* __restrict__ out_loss) {
  int t = threadIdx.x;
  float s = lsum[t];
#pragma unroll
  for (int off = 1; off < 64; off <<= 1) s += __shfl_xor(s, off, 64);
  __shared__ float a[4];
  if ((t & 63) == 0) a[t >> 6] = s;
  __syncthreads();
  if (t == 0) {
    float l = (a[0] + a[1] + a[2] + a[3]) / (float)(ROWS * H_);
    out_loss[0] = l; out_loss[1] = l;
  }
}

extern "C" void kernel_launch(void* const* d_in, const int* in_sizes, int n_in,
                              void* d_out, int out_size, void* d_ws, size_t ws_size,
                              hipStream_t stream) {
  (void)in_sizes; (void)n_in; (void)out_size; (void)ws_size;
  const float* hidden  = (const float*)d_in[0];
  const int* mask      = (const int*)d_in[1];
  const float* Wp      = (const float*)d_in[2];
  const float* codebook= (const float*)d_in[3];

  float* out = (float*)d_out;
  float* out_logits = out;                       // 8388608
  float* out_idx    = out + 8388608;             // 256
  float* out_preq   = out_idx + 256;             // 262144
  float* out_quant  = out_preq + 262144;         // 262144
  float* out_loss   = out_quant + 262144;        // 2

  // Early scratch lives inside the logits region (fully overwritten by dist_kernel later).
  float* part_pool = out_logits;                 // 16*32768 = 524288 floats
  int*   cntpart   = (int*)(out_logits + 524288);// 512
  float* pooledT   = out_logits + 524800;        // 32768
  int*   cnt       = (int*)(out_logits + 557568);// 32

  // Persistent-through-dist scratch in d_ws (~1.05 MB).
  float* ws     = (float*)d_ws;
  float* xnorm  = ws;                            // 256
  float* pscore = ws + 256;                      // 256*512
  int*   pidx   = (int*)(ws + 131328);           // 256*512
  float* lsum   = ws + 262400;                   // 256

  pool_kernel<<<dim3(B_, NCHUNK), 256, 0, stream>>>(hidden, mask, part_pool, cntpart);
  pool_reduce_kernel<<<128, 256, 0, stream>>>(part_pool, cntpart, pooledT, cnt);
  proj_kernel<<<1024, 256, 0, stream>>>(Wp, pooledT, cnt, out_preq);
  xnorm_kernel<<<ROWS, 256, 0, stream>>>(out_preq, xnorm);
  dist_kernel<<<V_ / NT, 256, 0, stream>>>(out_preq, codebook, xnorm, out_logits, pscore, pidx);
  finalize_kernel<<<ROWS, 256, 0, stream>>>(out_preq, codebook, pscore, pidx, out_idx, out_quant, lsum);
  loss_kernel<<<1, 256, 0, stream>>>(lsum, out_loss);
}

// Round 2
// 225.431 us; speedup vs baseline: 1.6595x; 1.6595x over previous
//
#include <hip/hip_runtime.h>

#define B_ 32
#define T_ 2048
#define H_ 1024
#define S_ 8
#define V_ 32768
#define ROWS 256    // B_*S_
#define OUTO 8192   // S_*H_
#define NCHUNK 16
#define TCHUNK 128
#define NBLK 256    // dist grid = V_/128

typedef __attribute__((ext_vector_type(8))) short s16x8;
typedef __attribute__((ext_vector_type(8))) unsigned short u16x8;
typedef __attribute__((ext_vector_type(4))) float f32x4;

// ---------------- kernel 1: masked pooling partials ----------------
__global__ void pool_kernel(const float* __restrict__ hidden,
                            const int* __restrict__ mask,
                            float* __restrict__ part_pool,   // [NCHUNK][H_*B_] as [h][b]
                            int* __restrict__ cntpart) {     // [NCHUNK][B_]
  int b = blockIdx.x;
  int chunk = blockIdx.y;
  int t0 = chunk * TCHUNK;
  int h4 = threadIdx.x * 4;
  const float* base = hidden + ((size_t)b * T_ + t0) * H_ + h4;
  const int* mrow = mask + (size_t)b * T_ + t0;
  float a0 = 0.f, a1 = 0.f, a2 = 0.f, a3 = 0.f;
  int mcount = 0;
#pragma unroll 4
  for (int i = 0; i < TCHUNK; ++i) {
    int mi = mrow[i];
    float m = (float)mi;
    mcount += mi;
    float4 v = *reinterpret_cast<const float4*>(base + (size_t)i * H_);
    a0 += m * v.x; a1 += m * v.y; a2 += m * v.z; a3 += m * v.w;
  }
  float* pp = part_pool + (size_t)chunk * (H_ * B_);
  pp[(h4 + 0) * B_ + b] = a0;
  pp[(h4 + 1) * B_ + b] = a1;
  pp[(h4 + 2) * B_ + b] = a2;
  pp[(h4 + 3) * B_ + b] = a3;
  if (threadIdx.x == 0) cntpart[chunk * B_ + b] = mcount;
}

// ---------------- kernel 1b: reduce partials -> pooledT [h][b] ----------------
__global__ void pool_reduce_kernel(const float* __restrict__ part_pool,
                                   const int* __restrict__ cntpart,
                                   float* __restrict__ pooledT,
                                   int* __restrict__ cnt) {
  int g = blockIdx.x * 256 + threadIdx.x;
  float s = 0.f;
  for (int c = 0; c < NCHUNK; ++c) s += part_pool[(size_t)c * (H_ * B_) + g];
  pooledT[g] = s;
  if (g < B_) {
    int cs = 0;
    for (int c = 0; c < NCHUNK; ++c) cs += cntpart[c * B_ + g];
    cnt[g] = cs;
  }
}

// ---------------- kernel 2: pre_q = pooled @ W^T ----------------
__global__ void proj_kernel(const float* __restrict__ Wp,
                            const float* __restrict__ pooledT,
                            const int* __restrict__ cnt,
                            float* __restrict__ preq) {
  int t = threadIdx.x;
  int olocal = t >> 5;
  int o = blockIdx.x * 8 + olocal;
  int b = t & 31;
  const float* wrow = Wp + (size_t)o * H_;
  float acc = 0.f;
#pragma unroll 4
  for (int k = 0; k < H_; k += 4) {
    float4 w4 = *reinterpret_cast<const float4*>(wrow + k);
    float p0 = pooledT[(k + 0) * B_ + b];
    float p1 = pooledT[(k + 1) * B_ + b];
    float p2 = pooledT[(k + 2) * B_ + b];
    float p3 = pooledT[(k + 3) * B_ + b];
    acc += w4.x * p0 + w4.y * p1 + w4.z * p2 + w4.w * p3;
  }
  float denom = fmaxf((float)cnt[b], 1.0f);
  float val = acc / denom;
  __shared__ float xch[8][32];
  xch[olocal][b] = val;
  __syncthreads();
  int b2 = t >> 3, j = t & 7;
  preq[(size_t)b2 * OUTO + blockIdx.x * 8 + j] = xch[j][b2];
}

// bf16 split: x ~= hi + lo (RNE hi, truncated lo)
__device__ __forceinline__ void bsplit(float x, unsigned short& h, unsigned short& s) {
  unsigned int u = __float_as_uint(x);
  unsigned int r = u + 0x7fffu + ((u >> 16) & 1u);
  h = (unsigned short)(r >> 16);
  float hf = __uint_as_float(r & 0xffff0000u);
  float lo = x - hf;
  s = (unsigned short)(__float_as_uint(lo) >> 16);
}

// ---------------- kernel 2b: split preq into MFMA-layout bf16 image + xnorm ----------------
// A_img layout (ushort units): [ks 0..31] { hi[256][32], lo[256][32] }  (16384 ushort per ks)
__global__ void aprep_kernel(const float* __restrict__ preq,
                             unsigned short* __restrict__ A_img,
                             float* __restrict__ xnorm) {
  int row = blockIdx.x;
  int t = threadIdx.x;            // 256 threads, 4 consecutive k each
  int k0 = 4 * t;
  int ks = k0 >> 5, kk = k0 & 31;
  float4 v = reinterpret_cast<const float4*>(preq + (size_t)row * H_)[t];
  float xv[4] = {v.x, v.y, v.z, v.w};
  unsigned short hv[4], lv[4];
  float s = 0.f;
#pragma unroll
  for (int i = 0; i < 4; ++i) { s += xv[i] * xv[i]; bsplit(xv[i], hv[i], lv[i]); }
  size_t base = (size_t)ks * 16384 + (size_t)row * 32 + kk;
  *reinterpret_cast<ushort4*>(&A_img[base])        = make_ushort4(hv[0], hv[1], hv[2], hv[3]);
  *reinterpret_cast<ushort4*>(&A_img[base + 8192]) = make_ushort4(lv[0], lv[1], lv[2], lv[3]);
#pragma unroll
  for (int off = 1; off < 64; off <<= 1) s += __shfl_xor(s, off);
  __shared__ float ps[4];
  if ((t & 63) == 0) ps[t >> 6] = s;
  __syncthreads();
  if (t == 0) xnorm[row] = ps[0] + ps[1] + ps[2] + ps[3];
}

// ---------------- kernel 3: split-bf16 MFMA distance GEMM + logits + block argmax ----------------
__global__ __launch_bounds__(512) void dist_kernel(
    const unsigned short* __restrict__ A_img, const float* __restrict__ codebook,
    const float* __restrict__ xnorm, float* __restrict__ logits,
    float* __restrict__ pscore, int* __restrict__ pidx) {
  __shared__ __align__(16) unsigned short Bs[2][128][40];  // [hi/lo][n][k] padded stride 40
  __shared__ float cn[128];
  __shared__ float xns[256];
  __shared__ float bwv[2][256];
  __shared__ int   bwi[2][256];

  const int t = threadIdx.x;
  const int l = t & 63;
  const int w = t >> 6;           // wave 0..7
  const int blk = blockIdx.x;
  const int v0 = blk * 128;
  const int m0 = (w >> 1) * 64;   // 4 row-slices of 64
  const int nb = (w & 1) * 64;    // 2 col-slices of 64
  const int lr = l & 15, lq = l >> 4;

  if (t < 256) xns[t] = xnorm[t];

  const int sn = t >> 2;          // staged codebook row 0..127
  const int sk = (t & 3) * 8;     // k offset within 32
  const float* cbp = codebook + (size_t)(v0 + sn) * H_ + sk;
  float csq = 0.f;

  f32x4 acc[4][4];
#pragma unroll
  for (int i = 0; i < 4; ++i)
#pragma unroll
    for (int j = 0; j < 4; ++j) acc[i][j] = (f32x4){0.f, 0.f, 0.f, 0.f};

  // prefetch first k-step
  float4 c0 = *reinterpret_cast<const float4*>(cbp);
  float4 c1 = *reinterpret_cast<const float4*>(cbp + 4);

  for (int ks = 0; ks < 32; ++ks) {
    __syncthreads();
    // convert the prefetched codebook 8-vector, write hi/lo LDS, accumulate ||c||^2
    {
      float xv[8] = {c0.x, c0.y, c0.z, c0.w, c1.x, c1.y, c1.z, c1.w};
      u16x8 hv, lv;
#pragma unroll
      for (int i = 0; i < 8; ++i) {
        float x = xv[i];
        csq += x * x;
        unsigned short hh, ll;
        bsplit(x, hh, ll);
        hv[i] = hh; lv[i] = ll;
      }
      *reinterpret_cast<u16x8*>(&Bs[0][sn][sk]) = hv;
      *reinterpret_cast<u16x8*>(&Bs[1][sn][sk]) = lv;
    }
    __syncthreads();
    // issue next k-step loads early (hidden under MFMAs)
    if (ks < 31) {
      c0 = *reinterpret_cast<const float4*>(cbp + (ks + 1) * 32);
      c1 = *reinterpret_cast<const float4*>(cbp + (ks + 1) * 32 + 4);
    }
    // A fragments: perfectly-coalesced 16B/lane global loads (L2-hot, 1MB image)
    const unsigned short* ab = A_img + (size_t)ks * 16384;
    s16x8 ah[4], al[4], bh[4], bl[4];
#pragma unroll
    for (int mt = 0; mt < 4; ++mt) {
      const unsigned short* p = ab + (size_t)(m0 + mt * 16 + lr) * 32 + lq * 8;
      ah[mt] = *reinterpret_cast<const s16x8*>(p);
      al[mt] = *reinterpret_cast<const s16x8*>(p + 8192);
    }
#pragma unroll
    for (int nt = 0; nt < 4; ++nt) {
      bh[nt] = *reinterpret_cast<const s16x8*>(&Bs[0][nb + nt * 16 + lr][lq * 8]);
      bl[nt] = *reinterpret_cast<const s16x8*>(&Bs[1][nb + nt * 16 + lr][lq * 8]);
    }
#pragma unroll
    for (int mt = 0; mt < 4; ++mt)
#pragma unroll
      for (int nt = 0; nt < 4; ++nt) {
        acc[mt][nt] = __builtin_amdgcn_mfma_f32_16x16x32_bf16(ah[mt], bh[nt], acc[mt][nt], 0, 0, 0);
        acc[mt][nt] = __builtin_amdgcn_mfma_f32_16x16x32_bf16(ah[mt], bl[nt], acc[mt][nt], 0, 0, 0);
        acc[mt][nt] = __builtin_amdgcn_mfma_f32_16x16x32_bf16(al[mt], bh[nt], acc[mt][nt], 0, 0, 0);
      }
  }

  // ||c||^2: reduce the 4 k-offset threads (consecutive lanes) of each staged row
  csq += __shfl_xor(csq, 1);
  csq += __shfl_xor(csq, 2);
  if ((t & 3) == 0) cn[sn] = csq;
  __syncthreads();

  // epilogue: logits + per-row best over this block's 128 cols
  const float NEG = -3.402823466e38f;
#pragma unroll
  for (int mt = 0; mt < 4; ++mt) {
#pragma unroll
    for (int r = 0; r < 4; ++r) {
      int row = m0 + mt * 16 + lq * 4 + r;
      float xn = xns[row];
      float bs = NEG; int bix = 0;
#pragma unroll
      for (int nt = 0; nt < 4; ++nt) {
        int col = nb + nt * 16 + lr;
        float sc = 2.f * acc[mt][nt][r] - cn[col];
        logits[(size_t)row * V_ + v0 + col] = sc - xn;
        if (sc > bs) { bs = sc; bix = v0 + col; }   // nt ascending => first-max tie-break
      }
#pragma unroll
      for (int off = 1; off < 16; off <<= 1) {     // reduce within 16-lane (same-row) group
        float os = __shfl_xor(bs, off);
        int oi = __shfl_xor(bix, off);
        if (os > bs || (os == bs && oi < bix)) { bs = os; bix = oi; }
      }
      if (lr == 0) { bwv[w & 1][row] = bs; bwi[w & 1][row] = bix; }
    }
  }
  __syncthreads();
  if (t < 256) {
    float b0 = bwv[0][t]; int i0 = bwi[0][t];
    float b1 = bwv[1][t]; int i1 = bwi[1][t];
    if (b1 > b0 || (b1 == b0 && i1 < i0)) { b0 = b1; i0 = i1; }
    pscore[(size_t)t * NBLK + blk] = b0;
    pidx[(size_t)t * NBLK + blk] = i0;
  }
}

// ---------------- kernel 4: per-row argmax over blocks, gather, quantized, loss partial ----------------
__global__ void finalize_kernel(const float* __restrict__ preq,
                                const float* __restrict__ codebook,
                                const float* __restrict__ pscore,
                                const int* __restrict__ pidx,
                                float* __restrict__ out_idx,
                                float* __restrict__ out_quant,
                                float* __restrict__ lsum) {
  int row = blockIdx.x;
  int t = threadIdx.x;
  float bs = -3.402823466e38f; int bi = 0x7fffffff;
  for (int p = t; p < NBLK; p += 256) {
    float s = pscore[(size_t)row * NBLK + p];
    int ix = pidx[(size_t)row * NBLK + p];
    if (s > bs || (s == bs && ix < bi)) { bs = s; bi = ix; }
  }
#pragma unroll
  for (int off = 1; off < 64; off <<= 1) {
    float os = __shfl_xor(bs, off);
    int oi = __shfl_xor(bi, off);
    if (os > bs || (os == bs && oi < bi)) { bs = os; bi = oi; }
  }
  __shared__ float ss[4]; __shared__ int si[4]; __shared__ int fidx;
  if ((t & 63) == 0) { ss[t >> 6] = bs; si[t >> 6] = bi; }
  __syncthreads();
  if (t == 0) {
    float b0 = ss[0]; int i0 = si[0];
    for (int wv = 1; wv < 4; ++wv)
      if (ss[wv] > b0 || (ss[wv] == b0 && si[wv] < i0)) { b0 = ss[wv]; i0 = si[wv]; }
    fidx = i0;
    out_idx[row] = (float)i0;
  }
  __syncthreads();
  int idx = fidx;
  float4 e = reinterpret_cast<const float4*>(codebook + (size_t)idx * H_)[t];
  float4 p = reinterpret_cast<const float4*>(preq + (size_t)row * H_)[t];
  float4 q;
  q.x = p.x + (e.x - p.x); q.y = p.y + (e.y - p.y);
  q.z = p.z + (e.z - p.z); q.w = p.w + (e.w - p.w);
  reinterpret_cast<float4*>(out_quant)[row * 256 + t] = q;
  float dx = p.x - e.x, dy = p.y - e.y, dz = p.z - e.z, dw = p.w - e.w;
  float ls = dx * dx + dy * dy + dz * dz + dw * dw;
#pragma unroll
  for (int off = 1; off < 64; off <<= 1) ls += __shfl_xor(ls, off);
  __shared__ float lss[4];
  if ((t & 63) == 0) lss[t >> 6] = ls;
  __syncthreads();
  if (t == 0) lsum[row] = lss[0] + lss[1] + lss[2] + lss[3];
}

// ---------------- kernel 5: final losses ----------------
__global__ void loss_kernel(const float* __restrict__ lsum, float* __restrict__ out_loss) {
  int t = threadIdx.x;
  float s = lsum[t];
#pragma unroll
  for (int off = 1; off < 64; off <<= 1) s += __shfl_xor(s, off);
  __shared__ float a[4];
  if ((t & 63) == 0) a[t >> 6] = s;
  __syncthreads();
  if (t == 0) {
    float lv = (a[0] + a[1] + a[2] + a[3]) / (float)(ROWS * H_);
    out_loss[0] = lv; out_loss[1] = lv;
  }
}

extern "C" void kernel_launch(void* const* d_in, const int* in_sizes, int n_in,
                              void* d_out, int out_size, void* d_ws, size_t ws_size,
                              hipStream_t stream) {
  (void)in_sizes; (void)n_in; (void)out_size; (void)ws_size;
  const float* hidden   = (const float*)d_in[0];
  const int* mask       = (const int*)d_in[1];
  const float* Wp       = (const float*)d_in[2];
  const float* codebook = (const float*)d_in[3];

  float* out = (float*)d_out;
  float* out_logits = out;                        // 8388608
  float* out_idx    = out + 8388608;              // 256
  float* out_preq   = out_idx + 256;              // 262144
  float* out_quant  = out_preq + 262144;          // 262144
  float* out_loss   = out_quant + 262144;         // 2

  // Early scratch inside logits region (fully overwritten by dist_kernel later).
  float* part_pool = out_logits;                  // 16*32768 floats
  int*   cntpart   = (int*)(out_logits + 524288); // 512
  float* pooledT   = out_logits + 524800;         // 32768
  int*   cnt       = (int*)(out_logits + 557568); // 32

  // d_ws scratch (~1.6 MB)
  float* ws     = (float*)d_ws;
  float* xnorm  = ws;                             // 256
  float* pscore = ws + 256;                       // 256*256
  int*   pidx   = (int*)(ws + 256 + 65536);       // 256*256
  float* lsum   = ws + 131328;                    // 256
  unsigned short* A_img = (unsigned short*)(ws + 131584);  // 1 MB

  pool_kernel<<<dim3(B_, NCHUNK), 256, 0, stream>>>(hidden, mask, part_pool, cntpart);
  pool_reduce_kernel<<<128, 256, 0, stream>>>(part_pool, cntpart, pooledT, cnt);
  proj_kernel<<<1024, 256, 0, stream>>>(Wp, pooledT, cnt, out_preq);
  aprep_kernel<<<ROWS, 256, 0, stream>>>(out_preq, A_img, xnorm);
  dist_kernel<<<NBLK, 512, 0, stream>>>(A_img, codebook, xnorm, out_logits, pscore, pidx);
  finalize_kernel<<<ROWS, 256, 0, stream>>>(out_preq, codebook, pscore, pidx, out_idx, out_quant, lsum);
  loss_kernel<<<1, 256, 0, stream>>>(lsum, out_loss);
}